// Round 1
// baseline (355.980 us; speedup 1.0000x reference)
//
#include <hip/hip_runtime.h>

#define PRO_NUM 64
#define TERM_NUM 512
#define MAX_LEN 1024
#define HID 256

typedef _Float16 f16x8 __attribute__((ext_vector_type(8)));
typedef _Float16 f16x4 __attribute__((ext_vector_type(4)));
typedef float f32x4 __attribute__((ext_vector_type(4)));

__device__ __forceinline__ f16x8 cvt8(const float* __restrict__ s) {
  float4 a = *(const float4*)s;
  float4 b = *(const float4*)(s + 4);
  f16x8 r = {(_Float16)a.x, (_Float16)a.y, (_Float16)a.z, (_Float16)a.w,
             (_Float16)b.x, (_Float16)b.y, (_Float16)b.z, (_Float16)b.w};
  return r;
}

// K1: pro f32 -> pro_h (f16, [p][l][h]) and proT (f16, [p][h][l]) via LDS tile transpose
__global__ __launch_bounds__(256) void k_convert(
    const float* __restrict__ pro, _Float16* __restrict__ pro_h,
    _Float16* __restrict__ proT) {
  __shared__ float tile[64][65];
  const int p = blockIdx.z;
  const int l0 = blockIdx.y * 64;
  const int h0 = blockIdx.x * 64;
  const int tid = threadIdx.x;
  const int rr = tid >> 4;         // 0..15
  const int cc = (tid & 15) * 4;   // 0..60
  const float* src = pro + ((size_t)p * MAX_LEN + l0) * HID + h0;
  #pragma unroll
  for (int j = 0; j < 4; ++j) {
    int r = rr + j * 16;
    float4 v = *(const float4*)(src + (size_t)r * HID + cc);
    tile[r][cc + 0] = v.x; tile[r][cc + 1] = v.y;
    tile[r][cc + 2] = v.z; tile[r][cc + 3] = v.w;
    f16x4 o = {(_Float16)v.x, (_Float16)v.y, (_Float16)v.z, (_Float16)v.w};
    *(f16x4*)(pro_h + ((size_t)p * MAX_LEN + l0 + r) * HID + h0 + cc) = o;
  }
  __syncthreads();
  #pragma unroll
  for (int j = 0; j < 4; ++j) {
    int hr = rr + j * 16;
    f16x4 o = {(_Float16)tile[cc + 0][hr], (_Float16)tile[cc + 1][hr],
               (_Float16)tile[cc + 2][hr], (_Float16)tile[cc + 3][hr]};
    *(f16x4*)(proT + ((size_t)p * HID + h0 + hr) * MAX_LEN + l0 + cc) = o;
  }
}

// K2: per (p, 16-term tile): scores = term @ pro^T (MFMA), masked softmax, write attn f32.
// Wave w owns l in [w*256, w*256+256) as 16 tiles of 16.
__global__ __launch_bounds__(256) void k_scores(
    const float* __restrict__ term, const _Float16* __restrict__ pro_h,
    const int* __restrict__ lens, float* __restrict__ attn) {
  const int p = blockIdx.y;
  const int t0 = blockIdx.x * 16;
  const int tid = threadIdx.x;
  const int w = tid >> 6;
  const int lane = tid & 63;
  const int lr = lane & 15;
  const int lg = lane >> 4;
  const int len = lens[p];

  // A fragments: term rows t0+lr, k = kk*32 + lg*8 + i  (f32 -> f16)
  f16x8 af[8];
  {
    const float* trow = term + (size_t)(t0 + lr) * HID + lg * 8;
    #pragma unroll
    for (int kk = 0; kk < 8; ++kk) af[kk] = cvt8(trow + kk * 32);
  }

  f32x4 acc[16];
  #pragma unroll
  for (int i = 0; i < 16; ++i) acc[i] = (f32x4){0.f, 0.f, 0.f, 0.f};

  // B fragments: B[k=h][n=l] = pro[l][h]; lane reads pro_h[p][l0+lr][kk*32+lg*8 .. +8]
  const _Float16* pbase = pro_h + ((size_t)p * MAX_LEN + w * 256 + lr) * HID + lg * 8;
  #pragma unroll
  for (int tile = 0; tile < 16; ++tile) {
    const _Float16* pr = pbase + (size_t)tile * 16 * HID;
    #pragma unroll
    for (int kk = 0; kk < 8; ++kk) {
      f16x8 bf = *(const f16x8*)(pr + kk * 32);
      acc[tile] = __builtin_amdgcn_mfma_f32_16x16x32_f16(af[kk], bf, acc[tile], 0, 0, 0);
    }
  }

  // mask + per-row max (row r -> t = t0 + lg*4 + r ; col = l = w*256 + tile*16 + lr)
  float rmax[4] = {-INFINITY, -INFINITY, -INFINITY, -INFINITY};
  #pragma unroll
  for (int tile = 0; tile < 16; ++tile) {
    int l = w * 256 + tile * 16 + lr;
    #pragma unroll
    for (int r = 0; r < 4; ++r) {
      float s = (l < len) ? acc[tile][r] : -INFINITY;
      acc[tile][r] = s;
      rmax[r] = fmaxf(rmax[r], s);
    }
  }
  #pragma unroll
  for (int m = 1; m < 16; m <<= 1) {
    #pragma unroll
    for (int r = 0; r < 4; ++r) rmax[r] = fmaxf(rmax[r], __shfl_xor(rmax[r], m));
  }
  __shared__ float rmx[4][16];
  __shared__ float rsm[4][16];
  if (lr == 0) {
    #pragma unroll
    for (int r = 0; r < 4; ++r) rmx[w][lg * 4 + r] = rmax[r];
  }
  __syncthreads();
  float fm[4];
  #pragma unroll
  for (int r = 0; r < 4; ++r) {
    int row = lg * 4 + r;
    fm[r] = fmaxf(fmaxf(rmx[0][row], rmx[1][row]), fmaxf(rmx[2][row], rmx[3][row]));
  }
  float rsum[4] = {0.f, 0.f, 0.f, 0.f};
  #pragma unroll
  for (int tile = 0; tile < 16; ++tile) {
    #pragma unroll
    for (int r = 0; r < 4; ++r) {
      float e = __expf(acc[tile][r] - fm[r]);  // masked (-inf) -> 0
      acc[tile][r] = e;
      rsum[r] += e;
    }
  }
  #pragma unroll
  for (int m = 1; m < 16; m <<= 1) {
    #pragma unroll
    for (int r = 0; r < 4; ++r) rsum[r] += __shfl_xor(rsum[r], m);
  }
  if (lr == 0) {
    #pragma unroll
    for (int r = 0; r < 4; ++r) rsm[w][lg * 4 + r] = rsum[r];
  }
  __syncthreads();
  float inv[4];
  #pragma unroll
  for (int r = 0; r < 4; ++r) {
    int row = lg * 4 + r;
    inv[r] = 1.0f / (rsm[0][row] + rsm[1][row] + rsm[2][row] + rsm[3][row]);
  }

  float* abase = attn + ((size_t)(p * TERM_NUM + t0 + lg * 4)) * MAX_LEN + w * 256 + lr;
  #pragma unroll
  for (int r = 0; r < 4; ++r) {
    float* arow = abase + (size_t)r * MAX_LEN;
    #pragma unroll
    for (int tile = 0; tile < 16; ++tile) arow[tile * 16] = acc[tile][r] * inv[r];
  }
}

// K3: out[p] = attn[p] (512x1024) @ pro[p] (1024x256), via proT so K(=l) is contiguous.
// Block: (p, 16-term tile); wave w owns h in [w*64, w*64+64) as 4 n-tiles.
__global__ __launch_bounds__(256) void k_pv(
    const float* __restrict__ attn, const _Float16* __restrict__ proT,
    float* __restrict__ out) {
  const int p = blockIdx.y;
  const int t0 = blockIdx.x * 16;
  const int tid = threadIdx.x;
  const int w = tid >> 6;
  const int lane = tid & 63;
  const int lr = lane & 15;
  const int lg = lane >> 4;

  f32x4 acc[4];
  #pragma unroll
  for (int i = 0; i < 4; ++i) acc[i] = (f32x4){0.f, 0.f, 0.f, 0.f};

  const float* arow = attn + ((size_t)p * TERM_NUM + t0 + lr) * MAX_LEN + lg * 8;
  const _Float16* brow = proT + ((size_t)p * HID + w * 64 + lr) * MAX_LEN + lg * 8;

  #pragma unroll 4
  for (int k0 = 0; k0 < MAX_LEN; k0 += 32) {
    f16x8 af = cvt8(arow + k0);
    #pragma unroll
    for (int nt = 0; nt < 4; ++nt) {
      f16x8 bf = *(const f16x8*)(brow + (size_t)nt * 16 * MAX_LEN + k0);
      acc[nt] = __builtin_amdgcn_mfma_f32_16x16x32_f16(af, bf, acc[nt], 0, 0, 0);
    }
  }

  float* obase = out + ((size_t)p * TERM_NUM + t0 + lg * 4) * HID + w * 64 + lr;
  #pragma unroll
  for (int nt = 0; nt < 4; ++nt) {
    #pragma unroll
    for (int r = 0; r < 4; ++r) obase[(size_t)r * HID + nt * 16] = acc[nt][r];
  }
}

extern "C" void kernel_launch(void* const* d_in, const int* in_sizes, int n_in,
                              void* d_out, int out_size, void* d_ws, size_t ws_size,
                              hipStream_t stream) {
  const float* term = (const float*)d_in[0];           // 512 x 256
  const float* pro  = (const float*)d_in[1];           // 64 x 1024 x 256
  const int*   lens = (const int*)d_in[2];             // 64

  float* out  = (float*)d_out;                                   // 64*512*256
  float* attn = out + (size_t)PRO_NUM * TERM_NUM * HID;          // 64*512*1024

  _Float16* pro_h = (_Float16*)d_ws;                             // 33.5 MB
  _Float16* proT  = pro_h + (size_t)PRO_NUM * MAX_LEN * HID;     // 33.5 MB

  k_convert<<<dim3(HID / 64, MAX_LEN / 64, PRO_NUM), 256, 0, stream>>>(pro, pro_h, proT);
  k_scores<<<dim3(TERM_NUM / 16, PRO_NUM), 256, 0, stream>>>(term, pro_h, lens, attn);
  k_pv<<<dim3(TERM_NUM / 16, PRO_NUM), 256, 0, stream>>>(attn, proT, out);
}

// Round 2
// 228.797 us; speedup vs baseline: 1.5559x; 1.5559x over previous
//
#include <hip/hip_runtime.h>

#define PRO_NUM 64
#define TERM_NUM 512
#define MAX_LEN 1024
#define HID 256

typedef _Float16 f16x8 __attribute__((ext_vector_type(8)));
typedef _Float16 f16x4 __attribute__((ext_vector_type(4)));
typedef float f32x4 __attribute__((ext_vector_type(4)));

__device__ __forceinline__ f16x8 cvt8(const float* __restrict__ s) {
  float4 a = *(const float4*)s;
  float4 b = *(const float4*)(s + 4);
  f16x8 r = {(_Float16)a.x, (_Float16)a.y, (_Float16)a.z, (_Float16)a.w,
             (_Float16)b.x, (_Float16)b.y, (_Float16)b.z, (_Float16)b.w};
  return r;
}

// K1: pro f32 -> pro_h (f16, [p][l][h]) and proT (f16, [p][h][l]) via LDS tile transpose
__global__ __launch_bounds__(256) void k_convert(
    const float* __restrict__ pro, _Float16* __restrict__ pro_h,
    _Float16* __restrict__ proT) {
  __shared__ float tile[64][65];
  const int p = blockIdx.z;
  const int l0 = blockIdx.y * 64;
  const int h0 = blockIdx.x * 64;
  const int tid = threadIdx.x;
  const int rr = tid >> 4;         // 0..15
  const int cc = (tid & 15) * 4;   // 0..60
  const float* src = pro + ((size_t)p * MAX_LEN + l0) * HID + h0;
  #pragma unroll
  for (int j = 0; j < 4; ++j) {
    int r = rr + j * 16;
    float4 v = *(const float4*)(src + (size_t)r * HID + cc);
    tile[r][cc + 0] = v.x; tile[r][cc + 1] = v.y;
    tile[r][cc + 2] = v.z; tile[r][cc + 3] = v.w;
    f16x4 o = {(_Float16)v.x, (_Float16)v.y, (_Float16)v.z, (_Float16)v.w};
    *(f16x4*)(pro_h + ((size_t)p * MAX_LEN + l0 + r) * HID + h0 + cc) = o;
  }
  __syncthreads();
  #pragma unroll
  for (int j = 0; j < 4; ++j) {
    int hr = rr + j * 16;
    f16x4 o = {(_Float16)tile[cc + 0][hr], (_Float16)tile[cc + 1][hr],
               (_Float16)tile[cc + 2][hr], (_Float16)tile[cc + 3][hr]};
    *(f16x4*)(proT + ((size_t)p * HID + h0 + hr) * MAX_LEN + l0 + cc) = o;
  }
}

// K2 (fused): per (p, 32-term tile): QK^T -> masked softmax -> write attn (global f32
// + LDS f16 swizzled) -> PV from LDS -> write out.
// Wave w owns l-range [w*256, w*256+256) in phases A/B; owns h-range [w*64, w*64+64) in phase C.
__global__ __launch_bounds__(256) void k_fused(
    const float* __restrict__ term, const _Float16* __restrict__ pro_h,
    const _Float16* __restrict__ proT, const int* __restrict__ lens,
    float* __restrict__ attn, float* __restrict__ out) {
  __shared__ __align__(16) _Float16 attn_lds[32][1024];  // 64 KB, XOR-swizzled cols
  __shared__ float rmx[4][32];
  __shared__ float rsm[4][32];

  // XCD-chunked swizzle: 1024 blocks, 8 XCDs, 128/XCD -> 8 p's per XCD chunk
  const int bid = blockIdx.x;
  const int swz = (bid & 7) * 128 + (bid >> 3);
  const int p = swz >> 4;
  const int t0 = (swz & 15) * 32;

  const int tid = threadIdx.x;
  const int w = tid >> 6;
  const int lane = tid & 63;
  const int lr = lane & 15;
  const int lg = lane >> 4;
  const int len = lens[p];
  const int l0w = w * 256;

  // tiles of 16 l-values this wave must actually compute (rest fully masked)
  int rem = len - l0w;
  int ntiles = rem <= 0 ? 0 : ((rem + 15) >> 4);
  if (ntiles > 16) ntiles = 16;

  // ---------------- Phase A: scores = term @ pro^T ----------------
  f32x4 acc[2][16];
  #pragma unroll
  for (int mt = 0; mt < 2; ++mt)
    #pragma unroll
    for (int i = 0; i < 16; ++i) acc[mt][i] = (f32x4){0.f, 0.f, 0.f, 0.f};

  const float* trow0 = term + (size_t)(t0 + lr) * HID + lg * 8;
  const _Float16* pb = pro_h + ((size_t)p * MAX_LEN + l0w + lr) * HID + lg * 8;

  #pragma unroll
  for (int kk = 0; kk < 8; ++kk) {
    f16x8 a0 = cvt8(trow0 + kk * 32);
    f16x8 a1 = cvt8(trow0 + (size_t)16 * HID + kk * 32);
    #pragma unroll
    for (int tile = 0; tile < 16; ++tile) {
      if (tile < ntiles) {  // wave-uniform predicate
        f16x8 bf = *(const f16x8*)(pb + (size_t)tile * 16 * HID + kk * 32);
        acc[0][tile] = __builtin_amdgcn_mfma_f32_16x16x32_f16(a0, bf, acc[0][tile], 0, 0, 0);
        acc[1][tile] = __builtin_amdgcn_mfma_f32_16x16x32_f16(a1, bf, acc[1][tile], 0, 0, 0);
      }
    }
  }

  // ---------------- Phase B: masked softmax ----------------
  float rmax[2][4];
  #pragma unroll
  for (int mt = 0; mt < 2; ++mt)
    #pragma unroll
    for (int r = 0; r < 4; ++r) rmax[mt][r] = -INFINITY;

  #pragma unroll
  for (int tile = 0; tile < 16; ++tile) {
    int l = l0w + tile * 16 + lr;
    #pragma unroll
    for (int mt = 0; mt < 2; ++mt) {
      #pragma unroll
      for (int r = 0; r < 4; ++r) {
        float s = (l < len) ? acc[mt][tile][r] : -INFINITY;
        acc[mt][tile][r] = s;
        rmax[mt][r] = fmaxf(rmax[mt][r], s);
      }
    }
  }
  #pragma unroll
  for (int m = 1; m < 16; m <<= 1) {
    #pragma unroll
    for (int mt = 0; mt < 2; ++mt)
      #pragma unroll
      for (int r = 0; r < 4; ++r) rmax[mt][r] = fmaxf(rmax[mt][r], __shfl_xor(rmax[mt][r], m));
  }
  if (lr == 0) {
    #pragma unroll
    for (int mt = 0; mt < 2; ++mt)
      #pragma unroll
      for (int r = 0; r < 4; ++r) rmx[w][mt * 16 + lg * 4 + r] = rmax[mt][r];
  }
  __syncthreads();
  float fm[2][4];
  #pragma unroll
  for (int mt = 0; mt < 2; ++mt)
    #pragma unroll
    for (int r = 0; r < 4; ++r) {
      int row = mt * 16 + lg * 4 + r;
      fm[mt][r] = fmaxf(fmaxf(rmx[0][row], rmx[1][row]), fmaxf(rmx[2][row], rmx[3][row]));
    }

  float rsum[2][4] = {{0.f, 0.f, 0.f, 0.f}, {0.f, 0.f, 0.f, 0.f}};
  #pragma unroll
  for (int tile = 0; tile < 16; ++tile) {
    #pragma unroll
    for (int mt = 0; mt < 2; ++mt) {
      #pragma unroll
      for (int r = 0; r < 4; ++r) {
        float e = __expf(acc[mt][tile][r] - fm[mt][r]);  // masked -> 0
        acc[mt][tile][r] = e;
        rsum[mt][r] += e;
      }
    }
  }
  #pragma unroll
  for (int m = 1; m < 16; m <<= 1) {
    #pragma unroll
    for (int mt = 0; mt < 2; ++mt)
      #pragma unroll
      for (int r = 0; r < 4; ++r) rsum[mt][r] += __shfl_xor(rsum[mt][r], m);
  }
  if (lr == 0) {
    #pragma unroll
    for (int mt = 0; mt < 2; ++mt)
      #pragma unroll
      for (int r = 0; r < 4; ++r) rsm[w][mt * 16 + lg * 4 + r] = rsum[mt][r];
  }
  __syncthreads();
  float inv[2][4];
  #pragma unroll
  for (int mt = 0; mt < 2; ++mt)
    #pragma unroll
    for (int r = 0; r < 4; ++r) {
      int row = mt * 16 + lg * 4 + r;
      inv[mt][r] = 1.0f / (rsm[0][row] + rsm[1][row] + rsm[2][row] + rsm[3][row]);
    }

  // write attn to global (f32 output) and LDS (f16, swizzled) in one pass
  #pragma unroll
  for (int mt = 0; mt < 2; ++mt) {
    #pragma unroll
    for (int r = 0; r < 4; ++r) {
      const int row = mt * 16 + lg * 4 + r;
      float* arow = attn + ((size_t)(p * TERM_NUM + t0 + row)) * MAX_LEN + l0w + lr;
      const int sw = (row & 7) << 3;
      #pragma unroll
      for (int tile = 0; tile < 16; ++tile) {
        float v = acc[mt][tile][r] * inv[mt][r];
        arow[tile * 16] = v;
        attn_lds[row][(l0w + tile * 16 + lr) ^ sw] = (_Float16)v;
      }
    }
  }
  __syncthreads();

  // ---------------- Phase C: out = attn @ pro ----------------
  f32x4 acc2[2][4];
  #pragma unroll
  for (int mt = 0; mt < 2; ++mt)
    #pragma unroll
    for (int nt = 0; nt < 4; ++nt) acc2[mt][nt] = (f32x4){0.f, 0.f, 0.f, 0.f};

  const _Float16* brow = proT + ((size_t)p * HID + w * 64 + lr) * MAX_LEN + lg * 8;
  const int kmax = (len + 31) & ~31;

  #pragma unroll 4
  for (int k0 = 0; k0 < kmax; k0 += 32) {
    f16x8 a[2];
    #pragma unroll
    for (int mt = 0; mt < 2; ++mt) {
      const int row = mt * 16 + lr;
      a[mt] = *(const f16x8*)&attn_lds[row][(k0 + lg * 8) ^ ((row & 7) << 3)];
    }
    #pragma unroll
    for (int nt = 0; nt < 4; ++nt) {
      f16x8 bf = *(const f16x8*)(brow + (size_t)nt * 16 * MAX_LEN + k0);
      acc2[0][nt] = __builtin_amdgcn_mfma_f32_16x16x32_f16(a[0], bf, acc2[0][nt], 0, 0, 0);
      acc2[1][nt] = __builtin_amdgcn_mfma_f32_16x16x32_f16(a[1], bf, acc2[1][nt], 0, 0, 0);
    }
  }

  #pragma unroll
  for (int mt = 0; mt < 2; ++mt) {
    #pragma unroll
    for (int nt = 0; nt < 4; ++nt) {
      #pragma unroll
      for (int r = 0; r < 4; ++r) {
        out[((size_t)p * TERM_NUM + t0 + mt * 16 + lg * 4 + r) * HID + w * 64 + nt * 16 + lr] =
            acc2[mt][nt][r];
      }
    }
  }
}

extern "C" void kernel_launch(void* const* d_in, const int* in_sizes, int n_in,
                              void* d_out, int out_size, void* d_ws, size_t ws_size,
                              hipStream_t stream) {
  const float* term = (const float*)d_in[0];           // 512 x 256
  const float* pro  = (const float*)d_in[1];           // 64 x 1024 x 256
  const int*   lens = (const int*)d_in[2];             // 64

  float* out  = (float*)d_out;                                   // 64*512*256
  float* attn = out + (size_t)PRO_NUM * TERM_NUM * HID;          // 64*512*1024

  _Float16* pro_h = (_Float16*)d_ws;                             // 33.5 MB
  _Float16* proT  = pro_h + (size_t)PRO_NUM * MAX_LEN * HID;     // 33.5 MB

  k_convert<<<dim3(HID / 64, MAX_LEN / 64, PRO_NUM), 256, 0, stream>>>(pro, pro_h, proT);
  k_fused<<<dim3(PRO_NUM * (TERM_NUM / 32)), 256, 0, stream>>>(term, pro_h, proT, lens, attn, out);
}